// Round 4
// baseline (782.258 us; speedup 1.0000x reference)
//
#include <hip/hip_runtime.h>

// MsgPassingNN: 3 rounds of edge-MLP + segment_sum + node-MLP.
// N=100000 nodes (D=16), E=3200000 edges.
// fe: 32 -> 9 (relu) -> 9 (relu) -> 9 ; fx: 25 -> 9 (relu) -> 9 (relu) -> 16
//
// R3 structure:
//   - Coarse bucket sort: bucket = dst>>7 (782 buckets of 128 nodes). Build via
//     per-block LDS histograms -> 306k global atomics (vs 3.2M full sort) and a
//     packed u32 (localdst<<17 | src) edge array (12.8 MB).
//   - Per round: p_k precomputes p[n] = W1_src^T x (9 floats tight, 3.6 MB,
//     L2-resident); round_k = one block per bucket: base1 (dst half of layer 1)
//     computed in-block, messages accumulated into LDS m[128][9] via ds_add_f32
//     (zero global atomics), node MLP fused as epilogue. Per-edge work: 36B
//     gather + ~171 FMA (layer 1 collapses to 9 adds).

constexpr int NN = 100000;
constexpr int NE = 3200000;
constexpr int NB = 782;              // ceil(100000/128)
constexpr int ABLK = 391;            // build blocks, 8192 edges each

typedef float float4a __attribute__((ext_vector_type(4), aligned(4)));

// ---------------- build: coarse bucket counting sort ----------------

__global__ __launch_bounds__(512) void bhist_k(const int* __restrict__ dst,
                                               int* __restrict__ gcnt,
                                               int* __restrict__ bbase)
{
    __shared__ int lcnt[NB];
    const int t = threadIdx.x;
    for (int i = t; i < NB; i += 512) lcnt[i] = 0;
    __syncthreads();
    const int e0 = blockIdx.x * 8192;
    #pragma unroll
    for (int k = 0; k < 16; ++k) {
        int e = e0 + k * 512 + t;
        if (e < NE) atomicAdd(&lcnt[dst[e] >> 7], 1);
    }
    __syncthreads();
    for (int b = t; b < NB; b += 512) {
        int c = lcnt[b];
        bbase[blockIdx.x * NB + b] = c ? atomicAdd(&gcnt[b], c) : 0;
    }
}

__global__ __launch_bounds__(1024) void scan_k(const int* __restrict__ gcnt,
                                               int* __restrict__ bstart)
{
    __shared__ int s[1024];
    const int t = threadIdx.x;
    int v = (t < NB) ? gcnt[t] : 0;
    s[t] = v;
    __syncthreads();
    for (int off = 1; off < 1024; off <<= 1) {
        int a = (t >= off) ? s[t - off] : 0;
        __syncthreads();
        s[t] += a;
        __syncthreads();
    }
    if (t < NB) bstart[t + 1] = s[t];
    if (t == 0) bstart[0] = 0;
}

__global__ __launch_bounds__(512) void bscatter_k(const int* __restrict__ src,
                                                  const int* __restrict__ dst,
                                                  const int* __restrict__ bstart,
                                                  const int* __restrict__ bbase,
                                                  unsigned* __restrict__ sed)
{
    __shared__ int lc[NB];
    const int t = threadIdx.x;
    for (int i = t; i < NB; i += 512) lc[i] = 0;
    __syncthreads();
    const int e0 = blockIdx.x * 8192;
    #pragma unroll
    for (int k = 0; k < 16; ++k) {
        int e = e0 + k * 512 + t;
        if (e < NE) {
            int d = dst[e];
            int b = d >> 7;
            int r = atomicAdd(&lc[b], 1);
            int pos = bstart[b] + bbase[blockIdx.x * NB + b] + r;
            sed[pos] = ((unsigned)(d & 127) << 17) | (unsigned)src[e];
        }
    }
}

// ---------------- per round: p = W1_src^T * X (no bias) ----------------

__global__ __launch_bounds__(256) void p_k(const float* __restrict__ X,
                                           const float* __restrict__ feW1,
                                           float* __restrict__ p)
{
    __shared__ float sW[144];
    const int t = threadIdx.x;
    if (t < 144) sW[t] = feW1[144 + t];   // src-half rows 16..31
    __syncthreads();
    const int n = blockIdx.x * 256 + t;
    if (n >= NN) return;
    float x[16];
    const float4* q = reinterpret_cast<const float4*>(X + (size_t)n * 16);
    #pragma unroll
    for (int k = 0; k < 4; ++k) {
        float4 v = q[k];
        x[4*k] = v.x; x[4*k+1] = v.y; x[4*k+2] = v.z; x[4*k+3] = v.w;
    }
    float acc[9];
    #pragma unroll
    for (int j = 0; j < 9; ++j) acc[j] = 0.f;
    #pragma unroll
    for (int i = 0; i < 16; ++i) {
        const float xi = x[i];
        #pragma unroll
        for (int j = 0; j < 9; ++j) acc[j] = fmaf(xi, sW[i * 9 + j], acc[j]);
    }
    float* pp = p + (size_t)n * 9;
    #pragma unroll
    for (int j = 0; j < 9; ++j) pp[j] = acc[j];
}

// ---------------- fused round: 1 block per 128-node bucket ----------------

__global__ __launch_bounds__(256) void round_k(
    const float* __restrict__ Xin,
    const unsigned* __restrict__ sed,
    const int* __restrict__ bstart,
    const float* __restrict__ feW1, const float* __restrict__ feb1,
    const float* __restrict__ feW2, const float* __restrict__ feb2,
    const float* __restrict__ feW3, const float* __restrict__ feb3,
    const float* __restrict__ fxW1, const float* __restrict__ fxb1,
    const float* __restrict__ fxW2, const float* __restrict__ fxb2,
    const float* __restrict__ fxW3, const float* __restrict__ fxb3,
    const float* __restrict__ p,
    float* __restrict__ Xout)
{
    __shared__ float sW1d[144], sb1[9];
    __shared__ float sW2[81], sb2[9], sW3[81], sb3[9];
    __shared__ float sU1[225], sU2[81], sU3[144], snb[34];
    __shared__ float base1L[128 * 12];
    __shared__ float mAcc[128 * 12];

    const int t = threadIdx.x;
    // weights -> LDS
    if (t < 81) { sW2[t] = feW2[t]; sW3[t] = feW3[t]; sU2[t] = fxW2[t]; }
    if (t < 144) { sW1d[t] = feW1[t]; sU3[t] = fxW3[t]; }
    for (int i = t; i < 225; i += 256) sU1[i] = fxW1[i];
    if (t < 9) { sb1[t] = feb1[t]; sb2[t] = feb2[t]; sb3[t] = feb3[t];
                 snb[t] = fxb1[t]; snb[9 + t] = fxb2[t]; }
    if (t < 16) snb[18 + t] = fxb3[t];
    for (int i = t; i < 128 * 12; i += 256) mAcc[i] = 0.f;
    __syncthreads();

    const int node0 = blockIdx.x << 7;
    const int nn = min(128, NN - node0);

    // base1 for own nodes: W1_dst^T x + b1
    if (t < nn) {
        float x[16];
        const float4* q = reinterpret_cast<const float4*>(Xin + (size_t)(node0 + t) * 16);
        #pragma unroll
        for (int k = 0; k < 4; ++k) {
            float4 v = q[k];
            x[4*k] = v.x; x[4*k+1] = v.y; x[4*k+2] = v.z; x[4*k+3] = v.w;
        }
        float b[9];
        #pragma unroll
        for (int j = 0; j < 9; ++j) b[j] = sb1[j];
        #pragma unroll
        for (int i = 0; i < 16; ++i) {
            const float xi = x[i];
            #pragma unroll
            for (int j = 0; j < 9; ++j) b[j] = fmaf(xi, sW1d[i * 9 + j], b[j]);
        }
        #pragma unroll
        for (int j = 0; j < 9; ++j) base1L[t * 12 + j] = b[j];
    }
    __syncthreads();

    // edge phase: dual-edge per iteration, LDS-atomic accumulate
    const int e0 = bstart[blockIdx.x];
    const int e1 = bstart[blockIdx.x + 1];
    for (int e = e0 + (t << 1); e < e1; e += 512) {
        const unsigned pk0 = sed[e];
        const bool v1 = (e + 1 < e1);
        const unsigned pk1 = sed[v1 ? e + 1 : e];
        const int s0 = (int)(pk0 & 0x1FFFFu), ld0 = (int)(pk0 >> 17);
        const int s1 = (int)(pk1 & 0x1FFFFu), ld1 = (int)(pk1 >> 17);

        float pf0[9], pf1[9];
        {
            const float* q0 = p + (size_t)s0 * 9;
            const float* q1 = p + (size_t)s1 * 9;
            float4a A0 = *(const float4a*)(q0);
            float4a B0 = *(const float4a*)(q0 + 4);
            float4a A1 = *(const float4a*)(q1);
            float4a B1 = *(const float4a*)(q1 + 4);
            pf0[0]=A0.x; pf0[1]=A0.y; pf0[2]=A0.z; pf0[3]=A0.w;
            pf0[4]=B0.x; pf0[5]=B0.y; pf0[6]=B0.z; pf0[7]=B0.w;
            pf0[8]=q0[8];
            pf1[0]=A1.x; pf1[1]=A1.y; pf1[2]=A1.z; pf1[3]=A1.w;
            pf1[4]=B1.x; pf1[5]=B1.y; pf1[6]=B1.z; pf1[7]=B1.w;
            pf1[8]=q1[8];
        }

        float a0[9], a1[9];
        #pragma unroll
        for (int j = 0; j < 9; ++j) {
            a0[j] = fmaxf(base1L[ld0 * 12 + j] + pf0[j], 0.f);
            a1[j] = fmaxf(base1L[ld1 * 12 + j] + pf1[j], 0.f);
        }
        float h0[9], h1[9];
        #pragma unroll
        for (int j = 0; j < 9; ++j) { h0[j] = sb2[j]; h1[j] = sb2[j]; }
        #pragma unroll
        for (int i = 0; i < 9; ++i) {
            const float x0 = a0[i], x1 = a1[i];
            #pragma unroll
            for (int j = 0; j < 9; ++j) {
                const float w = sW2[i * 9 + j];
                h0[j] = fmaf(x0, w, h0[j]);
                h1[j] = fmaf(x1, w, h1[j]);
            }
        }
        #pragma unroll
        for (int j = 0; j < 9; ++j) { h0[j] = fmaxf(h0[j], 0.f); h1[j] = fmaxf(h1[j], 0.f); }

        float o0[9], o1[9];
        #pragma unroll
        for (int j = 0; j < 9; ++j) { o0[j] = sb3[j]; o1[j] = sb3[j]; }
        #pragma unroll
        for (int i = 0; i < 9; ++i) {
            const float x0 = h0[i], x1 = h1[i];
            #pragma unroll
            for (int j = 0; j < 9; ++j) {
                const float w = sW3[i * 9 + j];
                o0[j] = fmaf(x0, w, o0[j]);
                o1[j] = fmaf(x1, w, o1[j]);
            }
        }
        #pragma unroll
        for (int j = 0; j < 9; ++j) atomicAdd(&mAcc[ld0 * 12 + j], o0[j]);
        if (v1) {
            #pragma unroll
            for (int j = 0; j < 9; ++j) atomicAdd(&mAcc[ld1 * 12 + j], o1[j]);
        }
    }
    __syncthreads();

    // node phase: fx MLP for own nodes
    if (t < nn) {
        float xr[16];
        const float4* q = reinterpret_cast<const float4*>(Xin + (size_t)(node0 + t) * 16);
        #pragma unroll
        for (int k = 0; k < 4; ++k) {
            float4 v = q[k];
            xr[4*k] = v.x; xr[4*k+1] = v.y; xr[4*k+2] = v.z; xr[4*k+3] = v.w;
        }
        float mm[9];
        #pragma unroll
        for (int j = 0; j < 9; ++j) mm[j] = mAcc[t * 12 + j];

        float h1v[9];
        #pragma unroll
        for (int j = 0; j < 9; ++j) h1v[j] = snb[j];
        #pragma unroll
        for (int i = 0; i < 16; ++i) {
            const float xi = xr[i];
            #pragma unroll
            for (int j = 0; j < 9; ++j) h1v[j] = fmaf(xi, sU1[i * 9 + j], h1v[j]);
        }
        #pragma unroll
        for (int i = 0; i < 9; ++i) {
            const float xi = mm[i];
            #pragma unroll
            for (int j = 0; j < 9; ++j) h1v[j] = fmaf(xi, sU1[(16 + i) * 9 + j], h1v[j]);
        }
        #pragma unroll
        for (int j = 0; j < 9; ++j) h1v[j] = fmaxf(h1v[j], 0.f);

        float h2[9];
        #pragma unroll
        for (int j = 0; j < 9; ++j) h2[j] = snb[9 + j];
        #pragma unroll
        for (int i = 0; i < 9; ++i) {
            const float xi = h1v[i];
            #pragma unroll
            for (int j = 0; j < 9; ++j) h2[j] = fmaf(xi, sU2[i * 9 + j], h2[j]);
        }
        #pragma unroll
        for (int j = 0; j < 9; ++j) h2[j] = fmaxf(h2[j], 0.f);

        float o[16];
        #pragma unroll
        for (int k = 0; k < 16; ++k) o[k] = snb[18 + k];
        #pragma unroll
        for (int j = 0; j < 9; ++j) {
            const float hj = h2[j];
            #pragma unroll
            for (int k = 0; k < 16; ++k) o[k] = fmaf(hj, sU3[j * 16 + k], o[k]);
        }
        float4* po = reinterpret_cast<float4*>(Xout + (size_t)(node0 + t) * 16);
        #pragma unroll
        for (int k = 0; k < 4; ++k) {
            float4 v;
            v.x = o[4*k]; v.y = o[4*k+1]; v.z = o[4*k+2]; v.w = o[4*k+3];
            po[k] = v;
        }
    }
}

extern "C" void kernel_launch(void* const* d_in, const int* in_sizes, int n_in,
                              void* d_out, int out_size, void* d_ws, size_t ws_size,
                              hipStream_t stream)
{
    const float* X0   = (const float*)d_in[0];
    const int*   esrc = (const int*)d_in[1];
    const int*   edst = (const int*)d_in[2];
    const float* feW1 = (const float*)d_in[3];
    const float* feb1 = (const float*)d_in[4];
    const float* feW2 = (const float*)d_in[5];
    const float* feb2 = (const float*)d_in[6];
    const float* feW3 = (const float*)d_in[7];
    const float* feb3 = (const float*)d_in[8];
    const float* fxW1 = (const float*)d_in[9];
    const float* fxb1 = (const float*)d_in[10];
    const float* fxW2 = (const float*)d_in[11];
    const float* fxb2 = (const float*)d_in[12];
    const float* fxW3 = (const float*)d_in[13];
    const float* fxb3 = (const float*)d_in[14];
    float* out = (float*)d_out;

    // workspace (4B units): ~30.5 MB
    float* Xa   = (float*)d_ws;                     // 1,600,000
    float* Xb   = Xa + (size_t)NN * 16;             // 1,600,000
    float* p    = Xb + (size_t)NN * 16;             // 900,000
    int* gcnt   = (int*)(p + (size_t)NN * 9);       // NB (+pad)
    int* bstart = gcnt + (NB + 2);                  // NB+1 (+pad)
    int* bbase  = bstart + (NB + 2);                // ABLK*NB = 305,762
    unsigned* sed = (unsigned*)(bbase + ABLK * NB); // NE u32

    const dim3 gA(ABLK), tA(512);
    const dim3 gN((NN + 255) / 256), tN(256);
    const dim3 gR(NB), tR(256);

    // ---- build (once per launch) ----
    hipMemsetAsync(gcnt, 0, (size_t)NB * sizeof(int), stream);
    bhist_k<<<gA, tA, 0, stream>>>(edst, gcnt, bbase);
    scan_k<<<1, 1024, 0, stream>>>(gcnt, bstart);
    bscatter_k<<<gA, tA, 0, stream>>>(esrc, edst, bstart, bbase, sed);

    // ---- 3 fused rounds: X0 -> Xa -> Xb -> out ----
    p_k<<<gN, tN, 0, stream>>>(X0, feW1, p);
    round_k<<<gR, tR, 0, stream>>>(X0, sed, bstart,
        feW1, feb1, feW2, feb2, feW3, feb3,
        fxW1, fxb1, fxW2, fxb2, fxW3, fxb3, p, Xa);

    p_k<<<gN, tN, 0, stream>>>(Xa, feW1, p);
    round_k<<<gR, tR, 0, stream>>>(Xa, sed, bstart,
        feW1, feb1, feW2, feb2, feW3, feb3,
        fxW1, fxb1, fxW2, fxb2, fxW3, fxb3, p, Xb);

    p_k<<<gN, tN, 0, stream>>>(Xb, feW1, p);
    round_k<<<gR, tR, 0, stream>>>(Xb, sed, bstart,
        feW1, feb1, feW2, feb2, feW3, feb3,
        fxW1, fxb1, fxW2, fxb2, fxW3, fxb3, p, out);
}